// Round 7
// baseline (243.657 us; speedup 1.0000x reference)
//
#include <hip/hip_runtime.h>
#include <hip/hip_bf16.h>

// z: [8,2048,32] f32 -> N=16384 rows, D=32 ; codebook: [8192,32] f32
// out: z_q_st (524288 f32) ++ idx (16384 f32) ++ loss (1 f32)
#define NROWS 16384
#define KCB   8192
#define DDIM  32
#define CSPLIT 8
#define COLS_PER_BLK (KCB / CSPLIT)            // 1024
#define TILES_PER_WAVE (COLS_PER_BLK / 16)     // 64
#define MARGIN 2.5e-4f

typedef __attribute__((ext_vector_type(8))) short short8;
typedef __attribute__((ext_vector_type(4))) float f32x4;

// ---------------- K1: normalize + bf16 hi/lo split + init ------------------
// Handles both z (rows 0..16383) and codebook (rows 16384..24575).
__global__ __launch_bounds__(256) void norm_split_kernel(
    const float* __restrict__ z, const float* __restrict__ cb,
    float* __restrict__ zn, float* __restrict__ en,
    float* __restrict__ zn2, float* __restrict__ en2,
    unsigned short* __restrict__ zh, unsigned short* __restrict__ zl,
    unsigned short* __restrict__ eh, unsigned short* __restrict__ el,
    double* __restrict__ lossacc, unsigned int* __restrict__ counters)
{
    int tid = threadIdx.x;
    if (blockIdx.x == 0) {
        if (tid == 0) *lossacc = 0.0;
        if (tid < 2) counters[tid] = 0u;
    }
    int grow = blockIdx.x * 8 + (tid >> 5);
    int l = tid & 31;
    const float* in; float* outv; float* outn2;
    unsigned short* oh; unsigned short* ol; int row;
    if (grow < NROWS) { in = z;  outv = zn; outn2 = zn2; oh = zh; ol = zl; row = grow; }
    else              { in = cb; outv = en; outn2 = en2; oh = eh; ol = el; row = grow - NROWS; }

    float x = in[(size_t)row * DDIM + l];
    float s = x * x;
#pragma unroll
    for (int m = 16; m >= 1; m >>= 1) s += __shfl_xor(s, m);
    float den = fmaxf(sqrtf(s), 1e-12f);
    float v = x / den;                       // IEEE div, matches F.normalize
    outv[(size_t)row * DDIM + l] = v;

    __hip_bfloat16 vh = __float2bfloat16(v);         // RNE
    float vhf = __bfloat162float(vh);
    __hip_bfloat16 vl = __float2bfloat16(v - vhf);   // residual (exact sub)
    oh[(size_t)row * DDIM + l] = *reinterpret_cast<unsigned short*>(&vh);
    ol[(size_t)row * DDIM + l] = *reinterpret_cast<unsigned short*>(&vl);

    float e = v * v;
#pragma unroll
    for (int m = 16; m >= 1; m >>= 1) e += __shfl_xor(e, m);
    if (l == 0) outn2[row] = e;              // post-norm squared norm (ref order)
}

// ---------------- K2: MFMA approx scores + per-row top-2 -------------------
// Block: 256 thr = 4 waves; wave handles 16 rows x COLS_PER_BLK cols.
// Approx score s' = e2[k] - 2*dot (z2 constant per row: dropped; margin
// analysis covers split + rounding error, bound ~2e-5 << MARGIN).
__global__ __launch_bounds__(256) void mfma_top2_kernel(
    const unsigned short* __restrict__ zh, const unsigned short* __restrict__ zl,
    const unsigned short* __restrict__ eh, const unsigned short* __restrict__ el,
    const float* __restrict__ en2,
    float* __restrict__ ps1, unsigned int* __restrict__ pk1,
    float* __restrict__ ps2)
{
    const int tid  = threadIdx.x;
    const int lane = tid & 63;
    const int wave = tid >> 6;
    const int lm   = lane & 15;    // A-row / B-col within tile
    const int lk   = lane >> 4;    // k-block (8 elems)
    const int rowbase = blockIdx.x * 64 + wave * 16;
    const int c0      = blockIdx.y * COLS_PER_BLK;

    // A fragments for this wave's 16 rows (held across all 64 tiles).
    short8 ah = *(const short8*)(zh + (size_t)(rowbase + lm) * DDIM + lk * 8);
    short8 al = *(const short8*)(zl + (size_t)(rowbase + lm) * DDIM + lk * 8);

    float        s1[4], s2[4];
    unsigned int k1[4];
#pragma unroll
    for (int r = 0; r < 4; ++r) {
        s1[r] = __int_as_float(0x7F800000);
        s2[r] = __int_as_float(0x7F800000);
        k1[r] = 0u;
    }

#pragma unroll 2
    for (int t = 0; t < TILES_PER_WAVE; ++t) {
        int col = c0 + t * 16;
        short8 bh = *(const short8*)(eh + (size_t)(col + lm) * DDIM + lk * 8);
        short8 bl = *(const short8*)(el + (size_t)(col + lm) * DDIM + lk * 8);
        float  e2 = en2[col + lm];

        f32x4 acc = {0.f, 0.f, 0.f, 0.f};
        acc = __builtin_amdgcn_mfma_f32_16x16x32_bf16(al, bh, acc, 0, 0, 0);
        acc = __builtin_amdgcn_mfma_f32_16x16x32_bf16(ah, bl, acc, 0, 0, 0);
        acc = __builtin_amdgcn_mfma_f32_16x16x32_bf16(ah, bh, acc, 0, 0, 0);

        unsigned int kc = (unsigned int)(col + lm);
#pragma unroll
        for (int r = 0; r < 4; ++r) {
            float sc = fmaf(-2.f, acc[r], e2);
            // top-2 update; k ascends over t per lane, strict < keeps first idx
            bool lt = sc < s1[r];
            k1[r] = lt ? kc : k1[r];
            float loser = fmaxf(sc, s1[r]);
            s1[r] = fminf(sc, s1[r]);
            s2[r] = fminf(s2[r], loser);
        }
    }

    // Cross-lane merge within each 16-lane column group (same lk => same rows).
#pragma unroll
    for (int m = 1; m < 16; m <<= 1) {
#pragma unroll
        for (int r = 0; r < 4; ++r) {
            float        os1 = __shfl_xor(s1[r], m);
            float        os2 = __shfl_xor(s2[r], m);
            unsigned int ok1 = __shfl_xor(k1[r], m);
            float hi  = fmaxf(s1[r], os1);
            float lo2 = fminf(s2[r], os2);
            bool  less = os1 < s1[r];
            bool  eq   = os1 == s1[r];
            unsigned int kmin = (k1[r] < ok1) ? k1[r] : ok1;
            k1[r] = less ? ok1 : (eq ? kmin : k1[r]);
            s1[r] = fminf(s1[r], os1);
            s2[r] = fminf(hi, lo2);
        }
    }

    if (lm == 0) {
#pragma unroll
        for (int r = 0; r < 4; ++r) {
            int row = rowbase + lk * 4 + r;
            size_t o = (size_t)blockIdx.y * NROWS + row;
            ps1[o] = s1[r]; pk1[o] = k1[r]; ps2[o] = s2[r];
        }
    }
}

// ---------------- K3: merge partials, flag ambiguous rows ------------------
__global__ __launch_bounds__(256) void merge_kernel(
    const float* __restrict__ ps1, const unsigned int* __restrict__ pk1,
    const float* __restrict__ ps2,
    int* __restrict__ best, unsigned int* __restrict__ counters,
    int* __restrict__ rescan_list)
{
    int row = blockIdx.x * 256 + threadIdx.x;
    float s1 = __int_as_float(0x7F800000);
    float s2 = __int_as_float(0x7F800000);
    unsigned int k1 = 0u;
#pragma unroll
    for (int b = 0; b < CSPLIT; ++b) {
        size_t o = (size_t)b * NROWS + row;
        float os1 = ps1[o]; float os2 = ps2[o]; unsigned int ok1 = pk1[o];
        float hi  = fmaxf(s1, os1);
        float lo2 = fminf(s2, os2);
        bool  less = os1 < s1;
        bool  eq   = os1 == s1;
        unsigned int kmin = (k1 < ok1) ? k1 : ok1;
        k1 = less ? ok1 : (eq ? kmin : k1);
        s1 = fminf(s1, os1);
        s2 = fminf(hi, lo2);
    }
    best[row] = (int)k1;
    if (s2 - s1 <= MARGIN) {
        unsigned int p = atomicAdd(&counters[1], 1u);
        rescan_list[p] = row;
    }
}

// ---------------- K4: exact fp32 rescore for ambiguous rows ----------------
// Replicates the round-2-validated exact formula: sequential fmaf d=0..31,
// s = fmaf(-2, dot, z2+e2), first-index tie-break via packed u64 min.
__global__ __launch_bounds__(256) void rescan_kernel(
    const float* __restrict__ zn, const float* __restrict__ en,
    const float* __restrict__ zn2, const float* __restrict__ en2,
    const unsigned int* __restrict__ counters,
    const int* __restrict__ rescan_list, int* __restrict__ best)
{
    __shared__ float zrow[DDIM];
    __shared__ unsigned long long wmin[4];
    unsigned int cnt = counters[1];
    for (unsigned int i = blockIdx.x; i < cnt; i += gridDim.x) {
        int row = rescan_list[i];
        if (threadIdx.x < DDIM) zrow[threadIdx.x] = zn[(size_t)row * DDIM + threadIdx.x];
        __syncthreads();
        float z2 = zn2[row];
        unsigned long long bestp = ~0ull;
        for (int j = 0; j < KCB / 256; ++j) {
            int k = threadIdx.x + 256 * j;           // ascending per thread
            const f32x4* er = (const f32x4*)(en + (size_t)k * DDIM);
            float acc = 0.f;
#pragma unroll
            for (int q = 0; q < 8; ++q) {
                f32x4 v = er[q];
                acc = fmaf(zrow[q * 4 + 0], v.x, acc);
                acc = fmaf(zrow[q * 4 + 1], v.y, acc);
                acc = fmaf(zrow[q * 4 + 2], v.z, acc);
                acc = fmaf(zrow[q * 4 + 3], v.w, acc);
            }
            float sc = fmaf(-2.f, acc, z2 + en2[k]);
            unsigned int u = __float_as_uint(sc);
            unsigned int sortable = u ^ (unsigned int)(((int)u >> 31) | 0x80000000);
            unsigned long long p =
                ((unsigned long long)sortable << 32) | (unsigned long long)k;
            bestp = (p < bestp) ? p : bestp;
        }
#pragma unroll
        for (int m = 1; m < 64; m <<= 1) {
            unsigned long long o = __shfl_xor(bestp, m);
            bestp = (o < bestp) ? o : bestp;
        }
        if ((threadIdx.x & 63) == 0) wmin[threadIdx.x >> 6] = bestp;
        __syncthreads();
        if (threadIdx.x == 0) {
            unsigned long long b0 = wmin[0] < wmin[1] ? wmin[0] : wmin[1];
            unsigned long long b1 = wmin[2] < wmin[3] ? wmin[2] : wmin[3];
            unsigned long long b  = b0 < b1 ? b0 : b1;
            best[row] = (int)(b & 0xFFFFFFFFull);
        }
        __syncthreads();
    }
}

// ---------------- K5: gather outputs + loss (last block finalizes) ---------
__global__ __launch_bounds__(256) void gather_out_kernel(
    const float* __restrict__ zn, const float* __restrict__ en,
    const int* __restrict__ best,
    float* __restrict__ out, float* __restrict__ outidx,
    float* __restrict__ outloss,
    double* __restrict__ lossacc, unsigned int* __restrict__ counters)
{
    int tid = threadIdx.x;
    int row = blockIdx.x * 8 + (tid >> 5);
    int l   = tid & 31;
    int idx = best[row];
    float zq = en[(size_t)idx * DDIM + l];   // l2_norm(codebook[idx])
    float zv = zn[(size_t)row * DDIM + l];
    float t  = zq - zv;
    out[(size_t)row * DDIM + l] = zv + t;    // straight-through
    if (l == 0) outidx[row] = (float)idx;

    float t2 = t * t;
    double s = (double)t2;
#pragma unroll
    for (int m = 32; m >= 1; m >>= 1) s += __shfl_xor(s, m);
    __shared__ double wsum[4];
    if ((tid & 63) == 0) wsum[tid >> 6] = s;
    __syncthreads();
    if (tid == 0) {
        double tot = wsum[0] + wsum[1] + wsum[2] + wsum[3];
        atomicAdd(lossacc, tot);
        __threadfence();
        unsigned int old = atomicAdd(&counters[0], 1u);
        if (old == (unsigned int)(gridDim.x - 1)) {
            double m = atomicAdd(lossacc, 0.0) / 524288.0;  // coherent read
            float mf = (float)m;
            *outloss = 0.25f * mf + mf;
        }
    }
}

// ---------------- launch ---------------------------------------------------
extern "C" void kernel_launch(void* const* d_in, const int* in_sizes, int n_in,
                              void* d_out, int out_size, void* d_ws, size_t ws_size,
                              hipStream_t stream)
{
    const float* z  = (const float*)d_in[0];
    const float* cb = (const float*)d_in[1];

    float* out     = (float*)d_out;
    float* outidx  = out + 524288;
    float* outloss = out + 540672;

    char* ws = (char*)d_ws;
    float*          zn       = (float*)(ws + 0);               // 2 MB
    float*          en       = (float*)(ws + 2097152);         // 1 MB
    unsigned short* zh       = (unsigned short*)(ws + 3145728);// 1 MB
    unsigned short* zl       = (unsigned short*)(ws + 4194304);// 1 MB
    unsigned short* eh       = (unsigned short*)(ws + 5242880);// 512 KB
    unsigned short* el       = (unsigned short*)(ws + 5767168);// 512 KB
    float*          zn2      = (float*)(ws + 6291456);         // 64 KB
    float*          en2      = (float*)(ws + 6356992);         // 32 KB
    float*          ps1      = (float*)(ws + 6389760);         // 512 KB
    unsigned int*   pk1      = (unsigned int*)(ws + 6914048);  // 512 KB
    float*          ps2      = (float*)(ws + 7438336);         // 512 KB
    int*            best     = (int*)(ws + 7962624);           // 64 KB
    int*            rescan   = (int*)(ws + 8028160);           // 64 KB
    double*         lossacc  = (double*)(ws + 8093696);
    unsigned int*   counters = (unsigned int*)(ws + 8093704);  // [2]

    norm_split_kernel<<<(NROWS + KCB) / 8, 256, 0, stream>>>(
        z, cb, zn, en, zn2, en2, zh, zl, eh, el, lossacc, counters);

    mfma_top2_kernel<<<dim3(NROWS / 64, CSPLIT), 256, 0, stream>>>(
        zh, zl, eh, el, en2, ps1, pk1, ps2);

    merge_kernel<<<NROWS / 256, 256, 0, stream>>>(
        ps1, pk1, ps2, best, counters, rescan);

    rescan_kernel<<<64, 256, 0, stream>>>(
        zn, en, zn2, en2, counters, rescan, best);

    gather_out_kernel<<<NROWS / 8, 256, 0, stream>>>(
        zn, en, best, out, outidx, outloss, lossacc, counters);
}

// Round 11
// 174.269 us; speedup vs baseline: 1.3982x; 1.3982x over previous
//
#include <hip/hip_runtime.h>
#include <hip/hip_bf16.h>

// z: [8,2048,32] f32 -> N=16384 rows, D=32 ; codebook: [8192,32] f32
// out: z_q_st (524288 f32) ++ idx (16384 f32) ++ loss (1 f32)
#define NROWS 16384
#define KCB   8192
#define DDIM  32
#define CSPLIT 8
#define COLS_PER_SPLIT (KCB / CSPLIT)         // 1024
#define CHUNK_COLS 128
#define NCHUNKS (COLS_PER_SPLIT / CHUNK_COLS) // 8
#define MARGIN 2.5e-4f

typedef __attribute__((ext_vector_type(8))) short short8;
typedef __attribute__((ext_vector_type(4))) float f32x4;
typedef __attribute__((ext_vector_type(4))) unsigned int u32x4;

// ---------------- K1: normalize + bf16 hi/lo split (round-7-proven + ehl) --
__global__ __launch_bounds__(256) void norm_split_kernel(
    const float* __restrict__ z, const float* __restrict__ cb,
    float* __restrict__ zn, float* __restrict__ en,
    float* __restrict__ zn2, float* __restrict__ en2,
    unsigned short* __restrict__ zh, unsigned short* __restrict__ zl,
    unsigned short* __restrict__ ehl, unsigned int* __restrict__ counters)
{
    int tid = threadIdx.x;
    if (blockIdx.x == 0 && tid < 2) counters[tid] = 0u;
    int grow = blockIdx.x * 8 + (tid >> 5);
    int l = tid & 31;
    bool isz = grow < NROWS;
    const float* in = isz ? z : cb;
    int row = isz ? grow : grow - NROWS;

    float x = in[(size_t)row * DDIM + l];
    float s = x * x;
#pragma unroll
    for (int m = 16; m >= 1; m >>= 1) s += __shfl_xor(s, m);
    float den = fmaxf(sqrtf(s), 1e-12f);
    float v = x / den;                       // IEEE div, matches F.normalize
    __hip_bfloat16 vh = __float2bfloat16(v);         // RNE
    float vhf = __bfloat162float(vh);
    __hip_bfloat16 vl = __float2bfloat16(v - vhf);   // residual (exact sub)
    unsigned short uh = *reinterpret_cast<unsigned short*>(&vh);
    unsigned short ul = *reinterpret_cast<unsigned short*>(&vl);
    float e = v * v;
#pragma unroll
    for (int m = 16; m >= 1; m >>= 1) e += __shfl_xor(e, m);

    if (isz) {
        zn[(size_t)row * DDIM + l] = v;
        zh[(size_t)row * DDIM + l] = uh;
        zl[(size_t)row * DDIM + l] = ul;
        if (l == 0) zn2[row] = e;
    } else {
        en[(size_t)row * DDIM + l] = v;
        ehl[(size_t)row * 64 + l]      = uh;   // shorts [0,32): hi
        ehl[(size_t)row * 64 + 32 + l] = ul;   // shorts [32,64): lo
        if (l == 0) en2[row] = e;              // post-norm squared norm (ref order)
    }
}

// ---------------- K2: MFMA scores + per-row top-2, LDS-staged B -------------
// Grid (128 rowblks, 8 col-splits). Block: 256 thr = 4 waves; wave owns 32
// rows (2 A-fragment pairs). B (ehl) staged per 128-col chunk into LDS with
// XOR swizzle: 16B unit of col r, slot o at addr o*2048+((r^o)<<4); reads
// factor to constant lane base + t*256 immediate (zero per-tile addr VALU).
// Uniform 8 chunks/chunk-column on both write & read -> no bank conflicts.
__global__ __launch_bounds__(256, 4) void mfma_top2_kernel(
    const unsigned short* __restrict__ zh, const unsigned short* __restrict__ zl,
    const unsigned short* __restrict__ ehl, const float* __restrict__ en2,
    float* __restrict__ ps1, unsigned int* __restrict__ pk1,
    float* __restrict__ ps2)
{
    __shared__ __align__(16) char lds[33792];  // 2x16KB B bufs + 2x512B e2 bufs
    const int tid  = threadIdx.x;
    const int lane = tid & 63, wave = tid >> 6;
    const int lm = lane & 15, lk = lane >> 4;
    const int rowbase = blockIdx.x * 128 + wave * 32;
    const int csp     = blockIdx.y;
    const int col0    = csp * COLS_PER_SPLIT;

    short8 ah0 = *(const short8*)(zh + (size_t)(rowbase + lm) * DDIM + lk * 8);
    short8 al0 = *(const short8*)(zl + (size_t)(rowbase + lm) * DDIM + lk * 8);
    short8 ah1 = *(const short8*)(zh + (size_t)(rowbase + 16 + lm) * DDIM + lk * 8);
    short8 al1 = *(const short8*)(zl + (size_t)(rowbase + 16 + lm) * DDIM + lk * 8);

    float s1[8], s2[8]; unsigned int k1[8];
#pragma unroll
    for (int r = 0; r < 8; ++r) {
        s1[r] = __int_as_float(0x7F800000);
        s2[r] = __int_as_float(0x7F800000);
        k1[r] = 0u;
    }

    const int bh_off = lk * 2048 + ((lm ^ lk) << 4);
    const int bl_off = (4 + lk) * 2048 + ((lm ^ (4 + lk)) << 4);

    auto STAGE = [&](int bsel, int colc) {
        char* dbuf = lds + bsel * 16384;
        const char* srcb = (const char*)ehl + (size_t)colc * 128;
#pragma unroll
        for (int s = 0; s < 4; ++s) {
            int e = s * 256 + tid;                 // 0..1023 (16B units)
            u32x4 v = *(const u32x4*)(srcb + (size_t)e * 16);
            int o = e & 7, r = e >> 3;
            *(u32x4*)(dbuf + o * 2048 + ((r ^ o) << 4)) = v;
        }
        if (tid < CHUNK_COLS)
            ((float*)(lds + 32768 + bsel * 512))[tid] = en2[colc + tid];
    };

    STAGE(0, col0);
    __syncthreads();
    for (int ch = 0; ch < NCHUNKS; ++ch) {
        if (ch + 1 < NCHUNKS) STAGE((ch + 1) & 1, col0 + (ch + 1) * CHUNK_COLS);
        const char* buf = lds + (ch & 1) * 16384;
        const float* e2b = (const float*)(lds + 32768 + (ch & 1) * 512);
#pragma unroll
        for (int t = 0; t < 8; ++t) {
            short8 bh = *(const short8*)(buf + bh_off + t * 256);
            short8 bl = *(const short8*)(buf + bl_off + t * 256);
            float e2 = e2b[t * 16 + lm];
            f32x4 acc0 = {0.f, 0.f, 0.f, 0.f};
            f32x4 acc1 = {0.f, 0.f, 0.f, 0.f};
            acc0 = __builtin_amdgcn_mfma_f32_16x16x32_bf16(al0, bh, acc0, 0, 0, 0);
            acc0 = __builtin_amdgcn_mfma_f32_16x16x32_bf16(ah0, bl, acc0, 0, 0, 0);
            acc0 = __builtin_amdgcn_mfma_f32_16x16x32_bf16(ah0, bh, acc0, 0, 0, 0);
            acc1 = __builtin_amdgcn_mfma_f32_16x16x32_bf16(al1, bh, acc1, 0, 0, 0);
            acc1 = __builtin_amdgcn_mfma_f32_16x16x32_bf16(ah1, bl, acc1, 0, 0, 0);
            acc1 = __builtin_amdgcn_mfma_f32_16x16x32_bf16(ah1, bh, acc1, 0, 0, 0);
            unsigned int kc = (unsigned int)(col0 + ch * CHUNK_COLS + t * 16 + lm);
#pragma unroll
            for (int r = 0; r < 4; ++r) {
                float sc0 = fmaf(-2.f, acc0[r], e2);
                // strict <: first index wins
                bool lt0 = sc0 < s1[r];
                k1[r] = lt0 ? kc : k1[r];
                float lo0 = fmaxf(sc0, s1[r]);
                s1[r] = fminf(sc0, s1[r]);
                s2[r] = fminf(s2[r], lo0);
                float sc1 = fmaf(-2.f, acc1[r], e2);
                bool lt1 = sc1 < s1[4 + r];
                k1[4 + r] = lt1 ? kc : k1[4 + r];
                float lo1 = fmaxf(sc1, s1[4 + r]);
                s1[4 + r] = fminf(sc1, s1[4 + r]);
                s2[4 + r] = fminf(s2[4 + r], lo1);
            }
        }
        __syncthreads();
    }

    // cross-lane merge within 16-lane column groups (same lk => same rows)
#pragma unroll
    for (int m = 1; m < 16; m <<= 1) {
#pragma unroll
        for (int r = 0; r < 8; ++r) {
            float        os1 = __shfl_xor(s1[r], m);
            float        os2 = __shfl_xor(s2[r], m);
            unsigned int ok1 = __shfl_xor(k1[r], m);
            float hi  = fmaxf(s1[r], os1);
            float lo2 = fminf(s2[r], os2);
            bool  less = os1 < s1[r];
            bool  eq   = os1 == s1[r];
            unsigned int kmin = (k1[r] < ok1) ? k1[r] : ok1;
            k1[r] = less ? ok1 : (eq ? kmin : k1[r]);
            s1[r] = fminf(s1[r], os1);
            s2[r] = fminf(hi, lo2);
        }
    }
    if (lm == 0) {
#pragma unroll
        for (int r = 0; r < 4; ++r) {
            int rowA = rowbase + lk * 4 + r;
            size_t oA = (size_t)csp * NROWS + rowA;
            ps1[oA] = s1[r]; pk1[oA] = k1[r]; ps2[oA] = s2[r];
            int rowB = rowbase + 16 + lk * 4 + r;
            size_t oB = (size_t)csp * NROWS + rowB;
            ps1[oB] = s1[4 + r]; pk1[oB] = k1[4 + r]; ps2[oB] = s2[4 + r];
        }
    }
}

// ---------------- K3: merge partials, flag ambiguous (round-7-proven) -------
__global__ __launch_bounds__(256) void merge_kernel(
    const float* __restrict__ ps1, const unsigned int* __restrict__ pk1,
    const float* __restrict__ ps2,
    int* __restrict__ best, unsigned int* __restrict__ counters,
    int* __restrict__ rescan_list)
{
    int row = blockIdx.x * 256 + threadIdx.x;
    float s1 = __int_as_float(0x7F800000);
    float s2 = __int_as_float(0x7F800000);
    unsigned int k1 = 0u;
#pragma unroll
    for (int b = 0; b < CSPLIT; ++b) {
        size_t o = (size_t)b * NROWS + row;
        float os1 = ps1[o]; float os2 = ps2[o]; unsigned int ok1 = pk1[o];
        float hi  = fmaxf(s1, os1);
        float lo2 = fminf(s2, os2);
        bool  less = os1 < s1;
        bool  eq   = os1 == s1;
        unsigned int kmin = (k1 < ok1) ? k1 : ok1;
        k1 = less ? ok1 : (eq ? kmin : k1);
        s1 = fminf(s1, os1);
        s2 = fminf(hi, lo2);
    }
    best[row] = (int)k1;
    if (s2 - s1 <= MARGIN) {
        unsigned int p = atomicAdd(&counters[1], 1u);
        rescan_list[p] = row;
    }
}

// ---------------- K4: exact fp32 rescore (round-7-proven) -------------------
__global__ __launch_bounds__(256) void rescan_kernel(
    const float* __restrict__ zn, const float* __restrict__ en,
    const float* __restrict__ zn2, const float* __restrict__ en2,
    const unsigned int* __restrict__ counters,
    const int* __restrict__ rescan_list, int* __restrict__ best)
{
    __shared__ float zrow[DDIM];
    __shared__ unsigned long long wmin[4];
    unsigned int cnt = counters[1];
    for (unsigned int i = blockIdx.x; i < cnt; i += gridDim.x) {
        int row = rescan_list[i];
        if (threadIdx.x < DDIM) zrow[threadIdx.x] = zn[(size_t)row * DDIM + threadIdx.x];
        __syncthreads();
        float z2 = zn2[row];
        unsigned long long bestp = ~0ull;
        for (int j = 0; j < KCB / 256; ++j) {
            int k = threadIdx.x + 256 * j;           // ascending per thread
            const f32x4* er = (const f32x4*)(en + (size_t)k * DDIM);
            float acc = 0.f;
#pragma unroll
            for (int q = 0; q < 8; ++q) {
                f32x4 v = er[q];
                acc = fmaf(zrow[q * 4 + 0], v.x, acc);
                acc = fmaf(zrow[q * 4 + 1], v.y, acc);
                acc = fmaf(zrow[q * 4 + 2], v.z, acc);
                acc = fmaf(zrow[q * 4 + 3], v.w, acc);
            }
            float sc = fmaf(-2.f, acc, z2 + en2[k]);
            unsigned int u = __float_as_uint(sc);
            unsigned int sortable = u ^ (unsigned int)(((int)u >> 31) | 0x80000000);
            unsigned long long p =
                ((unsigned long long)sortable << 32) | (unsigned long long)k;
            bestp = (p < bestp) ? p : bestp;
        }
#pragma unroll
        for (int m = 1; m < 64; m <<= 1) {
            unsigned long long o = __shfl_xor(bestp, m);
            bestp = (o < bestp) ? o : bestp;
        }
        if ((threadIdx.x & 63) == 0) wmin[threadIdx.x >> 6] = bestp;
        __syncthreads();
        if (threadIdx.x == 0) {
            unsigned long long b0 = wmin[0] < wmin[1] ? wmin[0] : wmin[1];
            unsigned long long b1 = wmin[2] < wmin[3] ? wmin[2] : wmin[3];
            unsigned long long b  = b0 < b1 ? b0 : b1;
            best[row] = (int)(b & 0xFFFFFFFFull);
        }
        __syncthreads();
    }
}

// ---------------- K5: gather outputs + per-block loss partial (no atomics) --
__global__ __launch_bounds__(256) void gather_kernel(
    const float* __restrict__ zn, const float* __restrict__ en,
    const int* __restrict__ best,
    float* __restrict__ out, float* __restrict__ outidx,
    double* __restrict__ lossp)
{
    int tid = threadIdx.x;
    int row = blockIdx.x * 8 + (tid >> 5);
    int l   = tid & 31;
    int idx = best[row];
    float zq = en[(size_t)idx * DDIM + l];   // l2_norm(codebook[idx])
    float zv = zn[(size_t)row * DDIM + l];
    float t  = zq - zv;
    out[(size_t)row * DDIM + l] = zv + t;    // straight-through
    if (l == 0) outidx[row] = (float)idx;

    double s = (double)(t * t);              // fp32 square like ref
#pragma unroll
    for (int m = 32; m >= 1; m >>= 1) s += __shfl_xor(s, m);
    __shared__ double wsum[4];
    if ((tid & 63) == 0) wsum[tid >> 6] = s;
    __syncthreads();
    if (tid == 0) lossp[blockIdx.x] = wsum[0] + wsum[1] + wsum[2] + wsum[3];
}

// ---------------- K6: finalize loss -----------------------------------------
__global__ __launch_bounds__(256) void finalize_kernel(
    const double* __restrict__ lossp, float* __restrict__ outloss)
{
    int tid = threadIdx.x;
    double v = 0.0;
#pragma unroll
    for (int j = 0; j < 8; ++j) v += lossp[tid + 256 * j];   // 2048 partials
#pragma unroll
    for (int m = 32; m >= 1; m >>= 1) v += __shfl_xor(v, m);
    __shared__ double wsum[4];
    if ((tid & 63) == 0) wsum[tid >> 6] = v;
    __syncthreads();
    if (tid == 0) {
        double mean = (wsum[0] + wsum[1] + wsum[2] + wsum[3]) / 524288.0;
        float mf = (float)mean;
        *outloss = 0.25f * mf + mf;          // BETA*m + m, ref rounding
    }
}

// ---------------- launch ---------------------------------------------------
extern "C" void kernel_launch(void* const* d_in, const int* in_sizes, int n_in,
                              void* d_out, int out_size, void* d_ws, size_t ws_size,
                              hipStream_t stream)
{
    const float* z  = (const float*)d_in[0];
    const float* cb = (const float*)d_in[1];

    float* out     = (float*)d_out;
    float* outidx  = out + 524288;
    float* outloss = out + 540672;

    char* ws = (char*)d_ws;
    float*          zn       = (float*)(ws + 0);                // 2 MB
    float*          en       = (float*)(ws + 2097152);          // 1 MB
    unsigned short* zh       = (unsigned short*)(ws + 3145728); // 1 MB
    unsigned short* zl       = (unsigned short*)(ws + 4194304); // 1 MB
    unsigned short* ehl      = (unsigned short*)(ws + 5242880); // 1 MB (hi|lo per row)
    float*          zn2      = (float*)(ws + 6291456);          // 64 KB
    float*          en2      = (float*)(ws + 6356992);          // 32 KB
    float*          ps1      = (float*)(ws + 6389760);          // 512 KB
    unsigned int*   pk1      = (unsigned int*)(ws + 6914048);   // 512 KB
    float*          ps2      = (float*)(ws + 7438336);          // 512 KB
    int*            best     = (int*)(ws + 7962624);            // 64 KB
    int*            rescan   = (int*)(ws + 8028160);            // 64 KB
    double*         lossp    = (double*)(ws + 8093696);         // 16 KB (2048 f64)
    unsigned int*   counters = (unsigned int*)(ws + 8110080);   // 64 B

    norm_split_kernel<<<(NROWS + KCB) / 8, 256, 0, stream>>>(
        z, cb, zn, en, zn2, en2, zh, zl, ehl, counters);

    mfma_top2_kernel<<<dim3(NROWS / 128, CSPLIT), 256, 0, stream>>>(
        zh, zl, ehl, en2, ps1, pk1, ps2);

    merge_kernel<<<NROWS / 256, 256, 0, stream>>>(
        ps1, pk1, ps2, best, counters, rescan);

    rescan_kernel<<<64, 256, 0, stream>>>(
        zn, en, zn2, en2, counters, rescan, best);

    gather_kernel<<<NROWS / 8, 256, 0, stream>>>(
        zn, en, best, out, outidx, lossp);

    finalize_kernel<<<1, 256, 0, stream>>>(lossp, outloss);
}

// Round 12
// 121.566 us; speedup vs baseline: 2.0043x; 1.4335x over previous
//
#include <hip/hip_runtime.h>
#include <hip/hip_bf16.h>

// z: [8,2048,32] f32 -> N=16384 rows, D=32 ; codebook: [8192,32] f32
// out: z_q_st (524288 f32) ++ idx (16384 f32) ++ loss (1 f32)
#define NROWS 16384
#define KCB   8192
#define DDIM  32
#define CSPLIT 8
#define COLS_PER_SPLIT (KCB / CSPLIT)         // 1024
#define CHUNK_COLS 128
#define NCHUNKS (COLS_PER_SPLIT / CHUNK_COLS) // 8
#define MARGIN 1.0e-4f
#define RESCAN_BLOCKS 512

typedef __attribute__((ext_vector_type(8))) short short8;
typedef __attribute__((ext_vector_type(4))) float f32x4;
typedef __attribute__((ext_vector_type(4))) unsigned int u32x4;

// ---------------- K1: normalize + bf16 hi/lo split (proven) -----------------
__global__ __launch_bounds__(256) void norm_split_kernel(
    const float* __restrict__ z, const float* __restrict__ cb,
    float* __restrict__ zn, float* __restrict__ en,
    float* __restrict__ zn2, float* __restrict__ en2,
    unsigned short* __restrict__ zh, unsigned short* __restrict__ zl,
    unsigned short* __restrict__ ehl, unsigned int* __restrict__ counters)
{
    int tid = threadIdx.x;
    if (blockIdx.x == 0 && tid < 2) counters[tid] = 0u;
    int grow = blockIdx.x * 8 + (tid >> 5);
    int l = tid & 31;
    bool isz = grow < NROWS;
    const float* in = isz ? z : cb;
    int row = isz ? grow : grow - NROWS;

    float x = in[(size_t)row * DDIM + l];
    float s = x * x;
#pragma unroll
    for (int m = 16; m >= 1; m >>= 1) s += __shfl_xor(s, m);
    float den = fmaxf(sqrtf(s), 1e-12f);
    float v = x / den;                       // IEEE div, matches F.normalize
    __hip_bfloat16 vh = __float2bfloat16(v);         // RNE
    float vhf = __bfloat162float(vh);
    __hip_bfloat16 vl = __float2bfloat16(v - vhf);   // residual (exact sub)
    unsigned short uh = *reinterpret_cast<unsigned short*>(&vh);
    unsigned short ul = *reinterpret_cast<unsigned short*>(&vl);
    float e = v * v;
#pragma unroll
    for (int m = 16; m >= 1; m >>= 1) e += __shfl_xor(e, m);

    if (isz) {
        zn[(size_t)row * DDIM + l] = v;
        zh[(size_t)row * DDIM + l] = uh;
        zl[(size_t)row * DDIM + l] = ul;
        if (l == 0) zn2[row] = e;
    } else {
        en[(size_t)row * DDIM + l] = v;
        ehl[(size_t)row * 64 + l]      = uh;   // shorts [0,32): hi
        ehl[(size_t)row * 64 + 32 + l] = ul;   // shorts [32,64): lo
        if (l == 0) en2[row] = e;              // post-norm squared norm (ref order)
    }
}

// ---------------- K2: MFMA scores + per-row top-2, LDS-staged B (proven) ----
__global__ __launch_bounds__(256, 4) void mfma_top2_kernel(
    const unsigned short* __restrict__ zh, const unsigned short* __restrict__ zl,
    const unsigned short* __restrict__ ehl, const float* __restrict__ en2,
    float* __restrict__ ps1, unsigned int* __restrict__ pk1,
    float* __restrict__ ps2)
{
    __shared__ __align__(16) char lds[33792];  // 2x16KB B bufs + 2x512B e2 bufs
    const int tid  = threadIdx.x;
    const int lane = tid & 63, wave = tid >> 6;
    const int lm = lane & 15, lk = lane >> 4;
    const int rowbase = blockIdx.x * 128 + wave * 32;
    const int csp     = blockIdx.y;
    const int col0    = csp * COLS_PER_SPLIT;

    short8 ah0 = *(const short8*)(zh + (size_t)(rowbase + lm) * DDIM + lk * 8);
    short8 al0 = *(const short8*)(zl + (size_t)(rowbase + lm) * DDIM + lk * 8);
    short8 ah1 = *(const short8*)(zh + (size_t)(rowbase + 16 + lm) * DDIM + lk * 8);
    short8 al1 = *(const short8*)(zl + (size_t)(rowbase + 16 + lm) * DDIM + lk * 8);

    float s1[8], s2[8]; unsigned int k1[8];
#pragma unroll
    for (int r = 0; r < 8; ++r) {
        s1[r] = __int_as_float(0x7F800000);
        s2[r] = __int_as_float(0x7F800000);
        k1[r] = 0u;
    }

    const int bh_off = lk * 2048 + ((lm ^ lk) << 4);
    const int bl_off = (4 + lk) * 2048 + ((lm ^ (4 + lk)) << 4);

    auto STAGE = [&](int bsel, int colc) {
        char* dbuf = lds + bsel * 16384;
        const char* srcb = (const char*)ehl + (size_t)colc * 128;
#pragma unroll
        for (int s = 0; s < 4; ++s) {
            int e = s * 256 + tid;                 // 0..1023 (16B units)
            u32x4 v = *(const u32x4*)(srcb + (size_t)e * 16);
            int o = e & 7, r = e >> 3;
            *(u32x4*)(dbuf + o * 2048 + ((r ^ o) << 4)) = v;
        }
        if (tid < CHUNK_COLS)
            ((float*)(lds + 32768 + bsel * 512))[tid] = en2[colc + tid];
    };

    STAGE(0, col0);
    __syncthreads();
    for (int ch = 0; ch < NCHUNKS; ++ch) {
        if (ch + 1 < NCHUNKS) STAGE((ch + 1) & 1, col0 + (ch + 1) * CHUNK_COLS);
        const char* buf = lds + (ch & 1) * 16384;
        const float* e2b = (const float*)(lds + 32768 + (ch & 1) * 512);
#pragma unroll
        for (int t = 0; t < 8; ++t) {
            short8 bh = *(const short8*)(buf + bh_off + t * 256);
            short8 bl = *(const short8*)(buf + bl_off + t * 256);
            float e2 = e2b[t * 16 + lm];
            f32x4 acc0 = {0.f, 0.f, 0.f, 0.f};
            f32x4 acc1 = {0.f, 0.f, 0.f, 0.f};
            acc0 = __builtin_amdgcn_mfma_f32_16x16x32_bf16(al0, bh, acc0, 0, 0, 0);
            acc0 = __builtin_amdgcn_mfma_f32_16x16x32_bf16(ah0, bl, acc0, 0, 0, 0);
            acc0 = __builtin_amdgcn_mfma_f32_16x16x32_bf16(ah0, bh, acc0, 0, 0, 0);
            acc1 = __builtin_amdgcn_mfma_f32_16x16x32_bf16(al1, bh, acc1, 0, 0, 0);
            acc1 = __builtin_amdgcn_mfma_f32_16x16x32_bf16(ah1, bl, acc1, 0, 0, 0);
            acc1 = __builtin_amdgcn_mfma_f32_16x16x32_bf16(ah1, bh, acc1, 0, 0, 0);
            unsigned int kc = (unsigned int)(col0 + ch * CHUNK_COLS + t * 16 + lm);
#pragma unroll
            for (int r = 0; r < 4; ++r) {
                float sc0 = fmaf(-2.f, acc0[r], e2);
                // strict <: first index wins
                bool lt0 = sc0 < s1[r];
                k1[r] = lt0 ? kc : k1[r];
                float lo0 = fmaxf(sc0, s1[r]);
                s1[r] = fminf(sc0, s1[r]);
                s2[r] = fminf(s2[r], lo0);
                float sc1 = fmaf(-2.f, acc1[r], e2);
                bool lt1 = sc1 < s1[4 + r];
                k1[4 + r] = lt1 ? kc : k1[4 + r];
                float lo1 = fmaxf(sc1, s1[4 + r]);
                s1[4 + r] = fminf(sc1, s1[4 + r]);
                s2[4 + r] = fminf(s2[4 + r], lo1);
            }
        }
        __syncthreads();
    }

    // cross-lane merge within 16-lane column groups (same lk => same rows)
#pragma unroll
    for (int m = 1; m < 16; m <<= 1) {
#pragma unroll
        for (int r = 0; r < 8; ++r) {
            float        os1 = __shfl_xor(s1[r], m);
            float        os2 = __shfl_xor(s2[r], m);
            unsigned int ok1 = __shfl_xor(k1[r], m);
            float hi  = fmaxf(s1[r], os1);
            float lo2 = fminf(s2[r], os2);
            bool  less = os1 < s1[r];
            bool  eq   = os1 == s1[r];
            unsigned int kmin = (k1[r] < ok1) ? k1[r] : ok1;
            k1[r] = less ? ok1 : (eq ? kmin : k1[r]);
            s1[r] = fminf(s1[r], os1);
            s2[r] = fminf(hi, lo2);
        }
    }
    if (lm == 0) {
#pragma unroll
        for (int r = 0; r < 4; ++r) {
            int rowA = rowbase + lk * 4 + r;
            size_t oA = (size_t)csp * NROWS + rowA;
            ps1[oA] = s1[r]; pk1[oA] = k1[r]; ps2[oA] = s2[r];
            int rowB = rowbase + 16 + lk * 4 + r;
            size_t oB = (size_t)csp * NROWS + rowB;
            ps1[oB] = s1[4 + r]; pk1[oB] = k1[4 + r]; ps2[oB] = s2[4 + r];
        }
    }
}

// ---------------- K3: merge partials; ambiguous -> sentinel + init best64 ---
__global__ __launch_bounds__(256) void merge_kernel(
    const float* __restrict__ ps1, const unsigned int* __restrict__ pk1,
    const float* __restrict__ ps2,
    int* __restrict__ best, unsigned long long* __restrict__ best64,
    unsigned int* __restrict__ counters, int* __restrict__ rescan_list)
{
    int row = blockIdx.x * 256 + threadIdx.x;
    float s1 = __int_as_float(0x7F800000);
    float s2 = __int_as_float(0x7F800000);
    unsigned int k1 = 0u;
#pragma unroll
    for (int b = 0; b < CSPLIT; ++b) {
        size_t o = (size_t)b * NROWS + row;
        float os1 = ps1[o]; float os2 = ps2[o]; unsigned int ok1 = pk1[o];
        float hi  = fmaxf(s1, os1);
        float lo2 = fminf(s2, os2);
        bool  less = os1 < s1;
        bool  eq   = os1 == s1;
        unsigned int kmin = (k1 < ok1) ? k1 : ok1;
        k1 = less ? ok1 : (eq ? kmin : k1);
        s1 = fminf(s1, os1);
        s2 = fminf(hi, lo2);
    }
    if (s2 - s1 <= MARGIN) {
        best[row] = -1;                      // sentinel: take best64 in gather
        best64[row] = ~0ull;
        unsigned int p = atomicAdd(&counters[1], 1u);
        rescan_list[p] = row;
    } else {
        best[row] = (int)k1;
    }
}

// ---------------- K4: exact rescore, fine-grained (row x col-slice) ---------
// Work item w: row = rescan_list[w>>3], cols [ (w&7)*1024, +1024 ).
// Exact packed (sortable score, k) u64 atomicMin -> global argmin with
// first-index tie-break; score formula bit-identical to round-2-validated.
__global__ __launch_bounds__(256) void rescan_kernel(
    const float* __restrict__ zn, const float* __restrict__ en,
    const float* __restrict__ zn2, const float* __restrict__ en2,
    const unsigned int* __restrict__ counters,
    const int* __restrict__ rescan_list, unsigned long long* __restrict__ best64)
{
    __shared__ float zrow[DDIM];
    unsigned int nwork = counters[1] * 8u;
    for (unsigned int w = blockIdx.x; w < nwork; w += gridDim.x) {
        int row = rescan_list[w >> 3];
        int c   = (int)(w & 7u);
        __syncthreads();                         // prev item's zrow reads done
        if (threadIdx.x < DDIM) zrow[threadIdx.x] = zn[(size_t)row * DDIM + threadIdx.x];
        __syncthreads();
        float z2 = zn2[row];
        unsigned long long bestp = ~0ull;
        int base = c * 1024;
#pragma unroll
        for (int j = 0; j < 4; ++j) {
            int k = base + threadIdx.x + 256 * j;
            const f32x4* er = (const f32x4*)(en + (size_t)k * DDIM);
            float acc = 0.f;
#pragma unroll
            for (int q = 0; q < 8; ++q) {
                f32x4 v = er[q];
                acc = fmaf(zrow[q * 4 + 0], v.x, acc);
                acc = fmaf(zrow[q * 4 + 1], v.y, acc);
                acc = fmaf(zrow[q * 4 + 2], v.z, acc);
                acc = fmaf(zrow[q * 4 + 3], v.w, acc);
            }
            float sc = fmaf(-2.f, acc, z2 + en2[k]);
            unsigned int u = __float_as_uint(sc);
            unsigned int sortable = u ^ (unsigned int)(((int)u >> 31) | 0x80000000);
            unsigned long long p =
                ((unsigned long long)sortable << 32) | (unsigned long long)k;
            bestp = (p < bestp) ? p : bestp;
        }
#pragma unroll
        for (int m = 1; m < 64; m <<= 1) {
            unsigned long long o = __shfl_xor(bestp, m);
            bestp = (o < bestp) ? o : bestp;
        }
        if ((threadIdx.x & 63) == 0) atomicMin(&best64[row], bestp);
    }
}

// ---------------- K5: gather outputs + per-block loss partial ---------------
__global__ __launch_bounds__(256) void gather_kernel(
    const float* __restrict__ zn, const float* __restrict__ en,
    const int* __restrict__ best, const unsigned long long* __restrict__ best64,
    float* __restrict__ out, float* __restrict__ outidx,
    double* __restrict__ lossp)
{
    int tid = threadIdx.x;
    int row = blockIdx.x * 8 + (tid >> 5);
    int l   = tid & 31;
    int b   = best[row];
    int idx = (b >= 0) ? b : (int)(best64[row] & 0xFFFFFFFFull);
    float zq = en[(size_t)idx * DDIM + l];   // l2_norm(codebook[idx])
    float zv = zn[(size_t)row * DDIM + l];
    float t  = zq - zv;
    out[(size_t)row * DDIM + l] = zv + t;    // straight-through
    if (l == 0) outidx[row] = (float)idx;

    double s = (double)(t * t);              // fp32 square like ref
#pragma unroll
    for (int m = 32; m >= 1; m >>= 1) s += __shfl_xor(s, m);
    __shared__ double wsum[4];
    if ((tid & 63) == 0) wsum[tid >> 6] = s;
    __syncthreads();
    if (tid == 0) lossp[blockIdx.x] = wsum[0] + wsum[1] + wsum[2] + wsum[3];
}

// ---------------- K6: finalize loss -----------------------------------------
__global__ __launch_bounds__(256) void finalize_kernel(
    const double* __restrict__ lossp, float* __restrict__ outloss)
{
    int tid = threadIdx.x;
    double v = 0.0;
#pragma unroll
    for (int j = 0; j < 8; ++j) v += lossp[tid + 256 * j];   // 2048 partials
#pragma unroll
    for (int m = 32; m >= 1; m >>= 1) v += __shfl_xor(v, m);
    __shared__ double wsum[4];
    if ((tid & 63) == 0) wsum[tid >> 6] = v;
    __syncthreads();
    if (tid == 0) {
        double mean = (wsum[0] + wsum[1] + wsum[2] + wsum[3]) / 524288.0;
        float mf = (float)mean;
        *outloss = 0.25f * mf + mf;          // BETA*m + m, ref rounding
    }
}

// ---------------- launch ---------------------------------------------------
extern "C" void kernel_launch(void* const* d_in, const int* in_sizes, int n_in,
                              void* d_out, int out_size, void* d_ws, size_t ws_size,
                              hipStream_t stream)
{
    const float* z  = (const float*)d_in[0];
    const float* cb = (const float*)d_in[1];

    float* out     = (float*)d_out;
    float* outidx  = out + 524288;
    float* outloss = out + 540672;

    char* ws = (char*)d_ws;
    float*          zn       = (float*)(ws + 0);                // 2 MB
    float*          en       = (float*)(ws + 2097152);          // 1 MB
    unsigned short* zh       = (unsigned short*)(ws + 3145728); // 1 MB
    unsigned short* zl       = (unsigned short*)(ws + 4194304); // 1 MB
    unsigned short* ehl      = (unsigned short*)(ws + 5242880); // 1 MB (hi|lo per row)
    float*          zn2      = (float*)(ws + 6291456);          // 64 KB
    float*          en2      = (float*)(ws + 6356992);          // 32 KB
    float*          ps1      = (float*)(ws + 6389760);          // 512 KB
    unsigned int*   pk1      = (unsigned int*)(ws + 6914048);   // 512 KB
    float*          ps2      = (float*)(ws + 7438336);          // 512 KB
    int*            best     = (int*)(ws + 7962624);            // 64 KB
    int*            rescan   = (int*)(ws + 8028160);            // 64 KB
    double*         lossp    = (double*)(ws + 8093696);         // 16 KB (2048 f64)
    unsigned int*   counters = (unsigned int*)(ws + 8110080);   // 64 B
    // best64 aliases zh: zh fully consumed by K2 before merge writes it.
    unsigned long long* best64 = (unsigned long long*)(ws + 3145728); // 128 KB

    norm_split_kernel<<<(NROWS + KCB) / 8, 256, 0, stream>>>(
        z, cb, zn, en, zn2, en2, zh, zl, ehl, counters);

    mfma_top2_kernel<<<dim3(NROWS / 128, CSPLIT), 256, 0, stream>>>(
        zh, zl, ehl, en2, ps1, pk1, ps2);

    merge_kernel<<<NROWS / 256, 256, 0, stream>>>(
        ps1, pk1, ps2, best, best64, counters, rescan);

    rescan_kernel<<<RESCAN_BLOCKS, 256, 0, stream>>>(
        zn, en, zn2, en2, counters, rescan, best64);

    gather_kernel<<<NROWS / 8, 256, 0, stream>>>(
        zn, en, best, best64, out, outidx, lossp);

    finalize_kernel<<<1, 256, 0, stream>>>(lossp, outloss);
}